// Round 16
// baseline (306.359 us; speedup 1.0000x reference)
//
#include <hip/hip_runtime.h>
#include <hip/hip_bf16.h>

#define N_EMBD 768
#define N_HEADS 12
#define HEAD_DIM 64

typedef __attribute__((ext_vector_type(4))) float f32x4;
typedef __attribute__((ext_vector_type(8))) short s16x8;

__device__ __forceinline__ float bf2f(unsigned short u) {
  union { unsigned int i; float f; } z;
  z.i = ((unsigned int)u) << 16;
  return z.f;
}

__device__ __forceinline__ void gload_lds16(const void* g, void* l) {
  __builtin_amdgcn_global_load_lds(
      (const __attribute__((address_space(1))) void*)g,
      (__attribute__((address_space(3))) void*)l, 16, 0, 0);
}

__device__ __forceinline__ float gelu_f(float x) {
  const float c = 0.7978845608028654f;
  float u = c * (x + 0.044715f * x * x * x);
  float t = 1.0f - 2.0f / (__expf(2.0f * u) + 1.0f);
  return 0.5f * x * (1.0f + t);
}

// ---------------- weight fp32 -> bf16 (all four in one launch) ----------------
__global__ void cvt4_kernel(const float* __restrict__ s0, __hip_bfloat16* d0,
                            const float* __restrict__ s1, __hip_bfloat16* d1,
                            const float* __restrict__ s2, __hip_bfloat16* d2,
                            const float* __restrict__ s3, __hip_bfloat16* d3,
                            int n0, int n1, int n2, int n3) {
  int i = blockIdx.x * 256 + threadIdx.x;
  if (i < n0) { d0[i] = __float2bfloat16(s0[i]); return; }
  i -= n0;
  if (i < n1) { d1[i] = __float2bfloat16(s1[i]); return; }
  i -= n1;
  if (i < n2) { d2[i] = __float2bfloat16(s2[i]); return; }
  i -= n2;
  if (i < n3) d3[i] = __float2bfloat16(s3[i]);
}

// ---------------- fused LayerNorm: fp32 in -> bf16 out ----------------
__global__ __launch_bounds__(256) void ln_kernel(
    const float* __restrict__ x, const float* __restrict__ g,
    const float* __restrict__ b, __hip_bfloat16* __restrict__ out) {
  __shared__ float red[8];
  const int row = blockIdx.x;
  const int tid = threadIdx.x;
  const float* xr = x + (size_t)row * N_EMBD;
  float v0 = xr[tid], v1 = xr[tid + 256], v2 = xr[tid + 512];
  float s = v0 + v1 + v2;
#pragma unroll
  for (int m = 32; m >= 1; m >>= 1) s += __shfl_xor(s, m);
  if ((tid & 63) == 0) red[tid >> 6] = s;
  __syncthreads();
  float mu = (red[0] + red[1] + red[2] + red[3]) * (1.0f / 768.0f);
  float d0 = v0 - mu, d1 = v1 - mu, d2 = v2 - mu;
  float ss = d0 * d0 + d1 * d1 + d2 * d2;
  __syncthreads();
#pragma unroll
  for (int m = 32; m >= 1; m >>= 1) ss += __shfl_xor(ss, m);
  if ((tid & 63) == 0) red[4 + (tid >> 6)] = ss;
  __syncthreads();
  float var = (red[4] + red[5] + red[6] + red[7]) * (1.0f / 768.0f);
  float rstd = rsqrtf(var + 1e-5f);
  __hip_bfloat16* orow = out + (size_t)row * N_EMBD;
  orow[tid]       = __float2bfloat16(d0 * rstd * g[tid]       + b[tid]);
  orow[tid + 256] = __float2bfloat16(d1 * rstd * g[tid + 256] + b[tid + 256]);
  orow[tid + 512] = __float2bfloat16(d2 * rstd * g[tid + 512] + b[tid + 512]);
}

// ---------------- 128x128 GEMM, counted-vmcnt + XOR swizzle (proj / FC2) ----------------
#define TILE_M 128
#define TILE_N 128
#define TILE_K 32

template <int EPI>
__global__ __launch_bounds__(256) void gemm_bt(
    const __hip_bfloat16* __restrict__ A, const __hip_bfloat16* __restrict__ W,
    const float* __restrict__ bias, const float* __restrict__ resid,
    __hip_bfloat16* __restrict__ outb, float* __restrict__ outf,
    int M, int N, int K) {
  __shared__ __hip_bfloat16 smA[2][TILE_M * TILE_K];
  __shared__ __hip_bfloat16 smB[2][TILE_N * TILE_K];
  const int tid = threadIdx.x;
  const int lane = tid & 63;
  const int wave = tid >> 6;

  const int nbx = gridDim.x;
  const int nwg = nbx * gridDim.y;
  int bid = blockIdx.y * nbx + blockIdx.x;
  if ((nwg & 7) == 0) bid = (bid & 7) * (nwg >> 3) + (bid >> 3);
  const int m0 = (bid / nbx) * TILE_M;
  const int n0 = (bid % nbx) * TILE_N;
  const int wr = wave >> 1, wc = wave & 1;

  f32x4 acc[4][4];
#pragma unroll
  for (int i = 0; i < 4; ++i)
#pragma unroll
    for (int j = 0; j < 4; ++j) acc[i][j] = f32x4{0.f, 0.f, 0.f, 0.f};

  const int ar0 = tid >> 2;
  const int ac0 = (((tid & 3) ^ ((ar0 >> 1) & 3))) * 8;
  const __hip_bfloat16* Abase0 = A + (size_t)(m0 + ar0) * K + ac0;
  const __hip_bfloat16* Abase1 = A + (size_t)(m0 + 64 + ar0) * K + ac0;
  const __hip_bfloat16* Wbase0 = W + (size_t)(n0 + ar0) * K + ac0;
  const __hip_bfloat16* Wbase1 = W + (size_t)(n0 + 64 + ar0) * K + ac0;

  auto stage = [&](int buf, int k0) {
    gload_lds16(Abase0 + k0, &smA[buf][wave * 512]);
    gload_lds16(Abase1 + k0, &smA[buf][2048 + wave * 512]);
    gload_lds16(Wbase0 + k0, &smB[buf][wave * 512]);
    gload_lds16(Wbase1 + k0, &smB[buf][2048 + wave * 512]);
  };

  const int rA = lane & 15;
  const int fq = lane >> 4;
  const int nk = K / TILE_K;

  stage(0, 0);

  int cur = 0;
  for (int t = 0; t < nk; ++t) {
    asm volatile("s_waitcnt vmcnt(0)" ::: "memory");
    asm volatile("s_barrier" ::: "memory");
    if (t + 1 < nk) stage(cur ^ 1, (t + 1) * TILE_K);

    s16x8 af[4], bfr[4];
#pragma unroll
    for (int mi = 0; mi < 4; ++mi) {
      const int row = wr * 64 + mi * 16 + rA;
      const int g = fq ^ ((row >> 1) & 3);
      af[mi] = *(const s16x8*)&smA[cur][row * TILE_K + g * 8];
    }
#pragma unroll
    for (int ni = 0; ni < 4; ++ni) {
      const int row = wc * 64 + ni * 16 + rA;
      const int g = fq ^ ((row >> 1) & 3);
      bfr[ni] = *(const s16x8*)&smB[cur][row * TILE_K + g * 8];
    }
#pragma unroll
    for (int mi = 0; mi < 4; ++mi)
#pragma unroll
      for (int ni = 0; ni < 4; ++ni)
        acc[mi][ni] = __builtin_amdgcn_mfma_f32_16x16x32_bf16(
            af[mi], bfr[ni], acc[mi][ni], 0, 0, 0);
    cur ^= 1;
  }

  const int crow = (lane >> 4) * 4;
  const int ccol = lane & 15;
#pragma unroll
  for (int mi = 0; mi < 4; ++mi) {
#pragma unroll
    for (int ni = 0; ni < 4; ++ni) {
      const int col = n0 + wc * 64 + ni * 16 + ccol;
      const float bv = bias[col];
#pragma unroll
      for (int j = 0; j < 4; ++j) {
        const int row = m0 + wr * 64 + mi * 16 + crow + j;
        float v = acc[mi][ni][j] + bv;
        const size_t o = (size_t)row * N + col;
        if (EPI == 0) {
          outb[o] = __float2bfloat16(v);
        } else if (EPI == 1) {
          outb[o] = __float2bfloat16(gelu_f(v));
        } else {
          outf[o] = resid[o] + v;
        }
      }
    }
  }
}

// ---------------- 256x256 8-phase GEMM (QKV / FC) — m201 template port ----------------
// 8 waves (2Mx4N, per-wave 128x64), BK=64, 2x64KB LDS dbuf. Per phase:
// {ds-read frag subtile; stage 1 half-tile (2 gload_lds); setprio+16 MFMA;
// raw s_barrier}. Counted vmcnt(4) only at phases 4 and 8 (2 half-tiles
// stay in flight across barriers); tail iter drains 0. Even tiles->lds[0],
// odd->lds[1]. Stage->phase map keeps every staged region >=1 barrier past
// its last reader (B restaged p3/p4 since B-frags reg-cached at p1/p5).
#define BM4 256
#define BN4 256
#define BK4 64

template <int EPI>
__global__ __launch_bounds__(512) void gemm8p(
    const __hip_bfloat16* __restrict__ A, const __hip_bfloat16* __restrict__ W,
    const float* __restrict__ bias,
    __hip_bfloat16* __restrict__ outb, int M, int N, int K) {
  __shared__ __align__(16) char lds[2][65536];  // [buf][A 32KB | B 32KB]
  const int tid = threadIdx.x;
  const int lane = tid & 63;
  const int wave = tid >> 6;
  const int wr = wave >> 2;   // 0..1 -> row half (128 rows)
  const int wc = wave & 3;    // 0..3 -> col quarter (64 cols)

  const int nbx = gridDim.x;
  const int nwg = nbx * gridDim.y;
  int bid = blockIdx.y * nbx + blockIdx.x;
  if ((nwg & 7) == 0) bid = (bid & 7) * (nwg >> 3) + (bid >> 3);
  const int m0 = (bid / nbx) * BM4;
  const int n0 = (bid % nbx) * BN4;

  f32x4 acc[8][4];
#pragma unroll
  for (int m = 0; m < 8; ++m)
#pragma unroll
    for (int n = 0; n < 4; ++n) acc[m][n] = f32x4{0.f, 0.f, 0.f, 0.f};

  // stage one 64-row slice (c in 0..3) of a 256x64 operand tile (verified math)
  auto sA = [&](int buf, int t, int c) {
    const int g = c * 512 + tid;
    const int row = g >> 3;
    const int col = ((g & 7) ^ (row & 7)) * 8;
    gload_lds16(A + (size_t)(m0 + row) * K + t * BK4 + col,
                lds[buf] + (c * 512 + wave * 64) * 16);
  };
  auto sB = [&](int buf, int t, int c) {
    const int g = c * 512 + tid;
    const int row = g >> 3;
    const int col = ((g & 7) ^ (row & 7)) * 8;
    gload_lds16(W + (size_t)(n0 + row) * K + t * BK4 + col,
                lds[buf] + 32768 + (c * 512 + wave * 64) * 16);
  };

  const int fr = lane & 15;
  const int fq = lane >> 4;
  const int nt = K / BK4;       // 12 for K=768
  const int niter = nt / 2;

  // prologue: tile0 full (A+B) + tile1 B; vmcnt(4) -> tile0 landed
#pragma unroll
  for (int c = 0; c < 4; ++c) sA(0, 0, c);
#pragma unroll
  for (int c = 0; c < 4; ++c) sB(0, 0, c);
#pragma unroll
  for (int c = 0; c < 4; ++c) sB(1, 1, c);
  asm volatile("s_waitcnt vmcnt(4)" ::: "memory");
  asm volatile("s_barrier" ::: "memory");

  s16x8 bfr[4][2];
  auto loadB = [&](const char* Bb) {
#pragma unroll
    for (int n = 0; n < 4; ++n)
#pragma unroll
      for (int kh = 0; kh < 2; ++kh) {
        const int row = wc * 64 + n * 16 + fr;
        const int gc = (kh * 4 + fq) ^ (row & 7);
        bfr[n][kh] = *(const s16x8*)(Bb + row * 128 + gc * 16);
      }
  };
  auto quad = [&](const char* Ab, int q) {
    s16x8 af[2][2];
#pragma unroll
    for (int m2 = 0; m2 < 2; ++m2)
#pragma unroll
      for (int kh = 0; kh < 2; ++kh) {
        const int row = wr * 128 + (2 * q + m2) * 16 + fr;
        const int gc = (kh * 4 + fq) ^ (row & 7);
        af[m2][kh] = *(const s16x8*)(Ab + row * 128 + gc * 16);
      }
    __builtin_amdgcn_s_setprio(1);
#pragma unroll
    for (int m2 = 0; m2 < 2; ++m2)
#pragma unroll
      for (int n = 0; n < 4; ++n)
#pragma unroll
        for (int kh = 0; kh < 2; ++kh)
          acc[2 * q + m2][n] = __builtin_amdgcn_mfma_f32_16x16x32_bf16(
              af[m2][kh], bfr[n][kh], acc[2 * q + m2][n], 0, 0, 0);
    __builtin_amdgcn_s_setprio(0);
  };

  for (int i = 0; i < niter; ++i) {
    const int t0 = 2 * i;
    const bool more2 = (t0 + 2 < nt);
    const bool more3 = (t0 + 3 < nt);
    const char* A0 = lds[0];
    const char* B0 = lds[0] + 32768;
    const char* A1 = lds[1];
    const char* B1 = lds[1] + 32768;

    // ---- phase 1: B(all)+A(q0) of tile t0; stage lds[1].Ah0 (tile t0+1)
    loadB(B0);
    sA(1, t0 + 1, 0); sA(1, t0 + 1, 1);
    quad(A0, 0);
    asm volatile("s_barrier" ::: "memory");
    // ---- phase 2: A(q1); stage lds[1].Ah1
    sA(1, t0 + 1, 2); sA(1, t0 + 1, 3);
    quad(A0, 1);
    asm volatile("s_barrier" ::: "memory");
    // ---- phase 3: A(q2); stage lds[0].Bh0 (tile t0+2)
    if (more2) { sB(0, t0 + 2, 0); sB(0, t0 + 2, 1); }
    quad(A0, 2);
    asm volatile("s_barrier" ::: "memory");
    // ---- phase 4: A(q3); stage lds[0].Bh1; counted vmcnt; barrier
    if (more2) { sB(0, t0 + 2, 2); sB(0, t0 + 2, 3); }
    quad(A0, 3);
    if (more2) asm volatile("s_waitcnt vmcnt(4)" ::: "memory");
    else       asm volatile("s_waitcnt vmcnt(0)" ::: "memory");
    asm volatile("s_barrier" ::: "memory");
    // ---- phase 5: B(all)+A(q0) of tile t0+1; stage lds[0].Ah0 (t0+2)
    loadB(B1);
    if (more2) { sA(0, t0 + 2, 0); sA(0, t0 + 2, 1); }
    quad(A1, 0);
    asm volatile("s_barrier" ::: "memory");
    // ---- phase 6: A(q1); stage lds[0].Ah1
    if (more2) { sA(0, t0 + 2, 2); sA(0, t0 + 2, 3); }
    quad(A1, 1);
    asm volatile("s_barrier" ::: "memory");
    // ---- phase 7: A(q2); stage lds[1].Bh0 (tile t0+3)
    if (more3) { sB(1, t0 + 3, 0); sB(1, t0 + 3, 1); }
    quad(A1, 2);
    asm volatile("s_barrier" ::: "memory");
    // ---- phase 8: A(q3); stage lds[1].Bh1; counted vmcnt; barrier
    if (more3) { sB(1, t0 + 3, 2); sB(1, t0 + 3, 3); }
    quad(A1, 3);
    if (more3) asm volatile("s_waitcnt vmcnt(4)" ::: "memory");
    else       asm volatile("s_waitcnt vmcnt(0)" ::: "memory");
    asm volatile("s_barrier" ::: "memory");
  }

  const int crow = fq * 4;
#pragma unroll
  for (int m = 0; m < 8; ++m) {
#pragma unroll
    for (int n = 0; n < 4; ++n) {
      const int col = n0 + wc * 64 + n * 16 + fr;
      const float bv = bias[col];
#pragma unroll
      for (int j = 0; j < 4; ++j) {
        const int row = m0 + wr * 128 + m * 16 + crow + j;
        float v = acc[m][n][j] + bv;
        const size_t o = (size_t)row * N + col;
        if (EPI == 0) outb[o] = __float2bfloat16(v);
        else outb[o] = __float2bfloat16(gelu_f(v));
      }
    }
  }
}

// ---------------- MFMA causal flash attention, v4 + packed P (R15) ----------------
#define AP 72

__global__ __launch_bounds__(256) void attn_mfma(
    const __hip_bfloat16* __restrict__ qkv, __hip_bfloat16* __restrict__ y,
    int T) {
  __shared__ __hip_bfloat16 ks[2][64 * AP];
  __shared__ __hip_bfloat16 vt[2][64 * AP];
  __shared__ __hip_bfloat16 ps[4][16 * AP];
  const int tid = threadIdx.x;
  const int lane = tid & 63;
  const int wave = tid >> 6;
  const int b = blockIdx.y / N_HEADS, h = blockIdx.y % N_HEADS;
  const int nq = T / 64;
  const int qa0 = blockIdx.x * 64;
  const int qb0 = (nq - 1 - blockIdx.x) * 64;
  const size_t ldq = 3 * N_EMBD;
  const __hip_bfloat16* qb_ = qkv + (size_t)b * T * ldq + h * HEAD_DIM;
  const __hip_bfloat16* kb = qb_ + N_EMBD;
  const __hip_bfloat16* vb = qb_ + 2 * N_EMBD;

  const int fr = lane & 15;
  const int fo = (lane >> 4) * 8;
  const int crow = (lane >> 4) * 4;

  const float qs = 0.125f * 1.44269504f;
  auto loadq = [&](int qrow, int o) -> s16x8 {
    s16x8 v = *(const s16x8*)(qb_ + (size_t)qrow * ldq + o);
    s16x8 r;
#pragma unroll
    for (int i = 0; i < 8; ++i) {
      float f = bf2f((unsigned short)v[i]) * qs;
      __hip_bfloat16 hb = __float2bfloat16(f);
      r[i] = *reinterpret_cast<short*>(&hb);
    }
    return r;
  };
  s16x8 qfa0 = loadq(qa0 + wave * 16 + fr, fo);
  s16x8 qfa1 = loadq(qa0 + wave * 16 + fr, fo + 32);
  s16x8 qfb0 = loadq(qb0 + wave * 16 + fr, fo);
  s16x8 qfb1 = loadq(qb0 + wave * 16 + fr, fo + 32);

  f32x4 oa[4], ob[4];
#pragma unroll
  for (int j = 0; j < 4; ++j) {
    oa[j] = f32x4{0.f, 0.f, 0.f, 0.f};
    ob[j] = f32x4{0.f, 0.f, 0.f, 0.f};
  }
  float m_a = -1e30f, l_a = 0.f, m_b = -1e30f, l_b = 0.f;

  s16x8 kr0, kr1, vr0, vr1;
  const int krow0 = tid >> 3;
  const int kcol = (tid & 7) * 8;
  const int vkey = 2 * (lane & 31);
  const int vd0 = wave * 16 + (lane >> 5) * 8;

  auto loadKV = [&](int kt) {
    kr0 = *(const s16x8*)(kb + (size_t)(kt + krow0) * ldq + kcol);
    kr1 = *(const s16x8*)(kb + (size_t)(kt + 32 + krow0) * ldq + kcol);
    vr0 = *(const s16x8*)(vb + (size_t)(kt + vkey) * ldq + vd0);
    vr1 = *(const s16x8*)(vb + (size_t)(kt + vkey + 1) * ldq + vd0);
  };
  auto writeKV = [&](int bufi) {
    *(s16x8*)&ks[bufi][krow0 * AP + kcol] = kr0;
    *(s16x8*)&ks[bufi][(32 + krow0) * AP + kcol] = kr1;
#pragma unroll
    for (int i = 0; i < 8; ++i) {
      unsigned u = (unsigned short)vr0[i] | ((unsigned)(unsigned short)vr1[i] << 16);
      *(unsigned*)&vt[bufi][(vd0 + i) * AP + vkey] = u;
    }
  };

  auto process = [&](int bufi, const s16x8& q0f, const s16x8& q1f,
                     f32x4 (&o)[4], float& m_, float& l_, int tq0, bool diag,
                     int kt) {
    f32x4 sv[4];
#pragma unroll
    for (int sub = 0; sub < 4; ++sub) {
      s16x8 k0 = *(const s16x8*)&ks[bufi][(sub * 16 + fr) * AP + fo];
      s16x8 k1 = *(const s16x8*)&ks[bufi][(sub * 16 + fr) * AP + 32 + fo];
      f32x4 acc = f32x4{0.f, 0.f, 0.f, 0.f};
      acc = __builtin_amdgcn_mfma_f32_16x16x32_bf16(k0, q0f, acc, 0, 0, 0);
      acc = __builtin_amdgcn_mfma_f32_16x16x32_bf16(k1, q1f, acc, 0, 0, 0);
      sv[sub] = acc;
    }
    const int qg = tq0 + wave * 16 + fr;
    if (diag) {
#pragma unroll
      for (int sub = 0; sub < 4; ++sub)
#pragma unroll
        for (int j = 0; j < 4; ++j)
          if (kt + sub * 16 + crow + j > qg) sv[sub][j] = -1e30f;
    }
    float t = fmaxf(fmaxf(sv[0][0], sv[0][1]), fmaxf(sv[0][2], sv[0][3]));
#pragma unroll
    for (int sub = 1; sub < 4; ++sub)
      t = fmaxf(t, fmaxf(fmaxf(sv[sub][0], sv[sub][1]),
                         fmaxf(sv[sub][2], sv[sub][3])));
    t = fmaxf(t, __shfl_xor(t, 16));
    t = fmaxf(t, __shfl_xor(t, 32));
    const bool resc = t > m_ + 8.0f;
    const float corr = resc ? exp2f(m_ - t) : 1.0f;
    if (resc) m_ = t;
    float rs = 0.f;
#pragma unroll
    for (int sub = 0; sub < 4; ++sub) {
      float p0 = exp2f(sv[sub][0] - m_);
      float p1 = exp2f(sv[sub][1] - m_);
      float p2 = exp2f(sv[sub][2] - m_);
      float p3 = exp2f(sv[sub][3] - m_);
      rs += p0 + p1 + p2 + p3;
      __hip_bfloat16 b0 = __float2bfloat16(p0), b1 = __float2bfloat16(p1);
      __hip_bfloat16 b2 = __float2bfloat16(p2), b3 = __float2bfloat16(p3);
      unsigned u01 = (unsigned)*(unsigned short*)&b0 |
                     ((unsigned)*(unsigned short*)&b1 << 16);
      unsigned u23 = (unsigned)*(unsigned short*)&b2 |
                     ((unsigned)*(unsigned short*)&b3 << 16);
      uint2 u; u.x = u01; u.y = u23;
      *(uint2*)&ps[wave][fr * AP + sub * 16 + crow] = u;
    }
    rs += __shfl_xor(rs, 16);
    rs += __shfl_xor(rs, 32);
    l_ = l_ * corr + rs;
    if (__any(resc)) {
#pragma unroll
      for (int j = 0; j < 4; ++j) {
        const float cj = __shfl(corr, (lane & 0x30) | (crow + j));
#pragma unroll
        for (int ds = 0; ds < 4; ++ds) o[ds][j] *= cj;
      }
    }
    s16x8 pf0 = *(const s16x8*)&ps[wave][fr * AP + fo];
    s16x8 pf1 = *(const s16x8*)&ps[wave][fr * AP + 32 + fo];
#pragma unroll
    for (int ds = 0; ds < 4; ++ds) {
      s16x8 v0 = *(const s16x8*)&vt[bufi][(ds * 16 + fr) * AP + fo];
      s16x8 v1 = *(const s16x8*)&vt[bufi][(ds * 16 + fr) * AP + 32 + fo];
      o[ds] = __builtin_amdgcn_mfma_f32_16x16x32_bf16(pf0, v0, o[ds], 0, 0, 0);
      o[ds] = __builtin_amdgcn_mfma_f32_16x16x32_bf16(pf1, v1, o[ds], 0, 0, 0);
    }
  };

  loadKV(0);
  writeKV(0);
  __syncthreads();
  int cur = 0;
  for (int kt = 0; kt <= qb0; kt += 64) {
    const bool hasnext = (kt + 64 <= qb0);
    if (hasnext) loadKV(kt + 64);
    if (kt <= qa0)
      process(cur, qfa0, qfa1, oa, m_a, l_a, qa0, kt == qa0, kt);
    process(cur, qfb0, qfb1, ob, m_b, l_b, qb0, kt == qb0, kt);
    if (hasnext) writeKV(cur ^ 1);
    __syncthreads();
    cur ^= 1;
  }

#pragma unroll
  for (int j = 0; j < 4; ++j) {
    const float la_j = __shfl(l_a, (lane & 0x30) | (crow + j));
    const float lb_j = __shfl(l_b, (lane & 0x30) | (crow + j));
    const float inva = 1.0f / la_j;
    const float invb = 1.0f / lb_j;
    __hip_bfloat16* ya =
        y + (size_t)(b * T + qa0 + wave * 16 + crow + j) * N_EMBD + h * HEAD_DIM;
    __hip_bfloat16* yb =
        y + (size_t)(b * T + qb0 + wave * 16 + crow + j) * N_EMBD + h * HEAD_DIM;
#pragma unroll
    for (int ds = 0; ds < 4; ++ds) {
      ya[ds * 16 + fr] = __float2bfloat16(oa[ds][j] * inva);
      yb[ds * 16 + fr] = __float2bfloat16(ob[ds][j] * invb);
    }
  }
}

// ---------------- launch ----------------
extern "C" void kernel_launch(void* const* d_in, const int* in_sizes, int n_in,
                              void* d_out, int out_size, void* d_ws,
                              size_t ws_size, hipStream_t stream) {
  const int B = 4, T = 2048, C = N_EMBD;
  const int M = B * T;  // 8192

  const float* x      = (const float*)d_in[0];
  const float* ln1_g  = (const float*)d_in[1];
  const float* ln1_b  = (const float*)d_in[2];
  const float* attn_w = (const float*)d_in[3];
  const float* attn_b = (const float*)d_in[4];
  const float* proj_w = (const float*)d_in[5];
  const float* proj_b = (const float*)d_in[6];
  const float* ln2_g  = (const float*)d_in[7];
  const float* ln2_b  = (const float*)d_in[8];
  const float* fc_w   = (const float*)d_in[9];
  const float* fc_b   = (const float*)d_in[10];
  const float* fc2_w  = (const float*)d_in[11];
  const float* fc2_b  = (const float*)d_in[12];
  float* out = (float*)d_out;

  char* p = (char*)d_ws;
  size_t off = 0;
  auto take = [&](size_t bytes) -> void* {
    void* q = p + off;
    off += (bytes + 1023) & ~(size_t)1023;
    return q;
  };

  __hip_bfloat16* wqkv  = (__hip_bfloat16*)take((size_t)3 * C * C * 2);
  __hip_bfloat16* wproj = (__hip_bfloat16*)take((size_t)C * C * 2);
  __hip_bfloat16* wfc   = (__hip_bfloat16*)take((size_t)4 * C * C * 2);
  __hip_bfloat16* wfc2  = (__hip_bfloat16*)take((size_t)4 * C * C * 2);
  __hip_bfloat16* hbuf  = (__hip_bfloat16*)take((size_t)M * C * 2);
  __hip_bfloat16* big   = (__hip_bfloat16*)take((size_t)M * 4 * C * 2);
  __hip_bfloat16* ybuf  = (__hip_bfloat16*)take((size_t)M * C * 2);
  float*          x1    = (float*)take((size_t)M * C * 4);

  {
    const int n0 = 3 * C * C, n1 = C * C, n2 = 4 * C * C, n3 = 4 * C * C;
    const int ntot = n0 + n1 + n2 + n3;
    cvt4_kernel<<<(ntot + 255) / 256, 256, 0, stream>>>(
        attn_w, wqkv, proj_w, wproj, fc_w, wfc, fc2_w, wfc2, n0, n1, n2, n3);
  }

  ln_kernel<<<M, 256, 0, stream>>>(x, ln1_g, ln1_b, hbuf);
  // QKV: [8192,2304], 8-phase 256^2 (grid 9x32 = 288, %8==0)
  gemm8p<0><<<dim3(3 * C / BN4, M / BM4), 512, 0, stream>>>(
      hbuf, wqkv, attn_b, big, M, 3 * C, C);
  attn_mfma<<<dim3(T / 128, B * N_HEADS), 256, 0, stream>>>(big, ybuf, T);
  gemm_bt<2><<<dim3(C / TILE_N, M / TILE_M), 256, 0, stream>>>(
      ybuf, wproj, proj_b, x, nullptr, x1, M, C, C);
  ln_kernel<<<M, 256, 0, stream>>>(x1, ln2_g, ln2_b, hbuf);
  // FC: [8192,3072] gelu, 8-phase 256^2 (grid 12x32 = 384, %8==0)
  gemm8p<1><<<dim3(4 * C / BN4, M / BM4), 512, 0, stream>>>(
      hbuf, wfc, fc_b, big, M, 4 * C, C);
  gemm_bt<2><<<dim3(C / TILE_N, M / TILE_M), 256, 0, stream>>>(
      big, wfc2, fc2_b, x1, nullptr, out, M, C, 4 * C);
}

// Round 17
// 299.326 us; speedup vs baseline: 1.0235x; 1.0235x over previous
//
#include <hip/hip_runtime.h>
#include <hip/hip_bf16.h>

#define N_EMBD 768
#define N_HEADS 12
#define HEAD_DIM 64

typedef __attribute__((ext_vector_type(4))) float f32x4;
typedef __attribute__((ext_vector_type(8))) short s16x8;

__device__ __forceinline__ float bf2f(unsigned short u) {
  union { unsigned int i; float f; } z;
  z.i = ((unsigned int)u) << 16;
  return z.f;
}

__device__ __forceinline__ void gload_lds16(const void* g, void* l) {
  __builtin_amdgcn_global_load_lds(
      (const __attribute__((address_space(1))) void*)g,
      (__attribute__((address_space(3))) void*)l, 16, 0, 0);
}

__device__ __forceinline__ float gelu_f(float x) {
  const float c = 0.7978845608028654f;
  float u = c * (x + 0.044715f * x * x * x);
  float t = 1.0f - 2.0f / (__expf(2.0f * u) + 1.0f);
  return 0.5f * x * (1.0f + t);
}

// ---------------- weight fp32 -> bf16 (all four in one launch) ----------------
__global__ void cvt4_kernel(const float* __restrict__ s0, __hip_bfloat16* d0,
                            const float* __restrict__ s1, __hip_bfloat16* d1,
                            const float* __restrict__ s2, __hip_bfloat16* d2,
                            const float* __restrict__ s3, __hip_bfloat16* d3,
                            int n0, int n1, int n2, int n3) {
  int i = blockIdx.x * 256 + threadIdx.x;
  if (i < n0) { d0[i] = __float2bfloat16(s0[i]); return; }
  i -= n0;
  if (i < n1) { d1[i] = __float2bfloat16(s1[i]); return; }
  i -= n1;
  if (i < n2) { d2[i] = __float2bfloat16(s2[i]); return; }
  i -= n2;
  if (i < n3) d3[i] = __float2bfloat16(s3[i]);
}

// ---------------- fused LayerNorm: fp32 in -> bf16 out ----------------
__global__ __launch_bounds__(256) void ln_kernel(
    const float* __restrict__ x, const float* __restrict__ g,
    const float* __restrict__ b, __hip_bfloat16* __restrict__ out) {
  __shared__ float red[8];
  const int row = blockIdx.x;
  const int tid = threadIdx.x;
  const float* xr = x + (size_t)row * N_EMBD;
  float v0 = xr[tid], v1 = xr[tid + 256], v2 = xr[tid + 512];
  float s = v0 + v1 + v2;
#pragma unroll
  for (int m = 32; m >= 1; m >>= 1) s += __shfl_xor(s, m);
  if ((tid & 63) == 0) red[tid >> 6] = s;
  __syncthreads();
  float mu = (red[0] + red[1] + red[2] + red[3]) * (1.0f / 768.0f);
  float d0 = v0 - mu, d1 = v1 - mu, d2 = v2 - mu;
  float ss = d0 * d0 + d1 * d1 + d2 * d2;
  __syncthreads();
#pragma unroll
  for (int m = 32; m >= 1; m >>= 1) ss += __shfl_xor(ss, m);
  if ((tid & 63) == 0) red[4 + (tid >> 6)] = ss;
  __syncthreads();
  float var = (red[4] + red[5] + red[6] + red[7]) * (1.0f / 768.0f);
  float rstd = rsqrtf(var + 1e-5f);
  __hip_bfloat16* orow = out + (size_t)row * N_EMBD;
  orow[tid]       = __float2bfloat16(d0 * rstd * g[tid]       + b[tid]);
  orow[tid + 256] = __float2bfloat16(d1 * rstd * g[tid + 256] + b[tid + 256]);
  orow[tid + 512] = __float2bfloat16(d2 * rstd * g[tid + 512] + b[tid + 512]);
}

// ---------------- 128x128 GEMM, counted-vmcnt + XOR swizzle (QKV / FC) ----------------
#define TILE_M 128
#define TILE_N 128
#define TILE_K 32

template <int EPI>
__global__ __launch_bounds__(256) void gemm_bt(
    const __hip_bfloat16* __restrict__ A, const __hip_bfloat16* __restrict__ W,
    const float* __restrict__ bias, const float* __restrict__ resid,
    __hip_bfloat16* __restrict__ outb, float* __restrict__ outf,
    int M, int N, int K) {
  __shared__ __hip_bfloat16 smA[2][TILE_M * TILE_K];
  __shared__ __hip_bfloat16 smB[2][TILE_N * TILE_K];
  const int tid = threadIdx.x;
  const int lane = tid & 63;
  const int wave = tid >> 6;

  const int nbx = gridDim.x;
  const int nwg = nbx * gridDim.y;
  int bid = blockIdx.y * nbx + blockIdx.x;
  if ((nwg & 7) == 0) bid = (bid & 7) * (nwg >> 3) + (bid >> 3);
  const int m0 = (bid / nbx) * TILE_M;
  const int n0 = (bid % nbx) * TILE_N;
  const int wr = wave >> 1, wc = wave & 1;

  f32x4 acc[4][4];
#pragma unroll
  for (int i = 0; i < 4; ++i)
#pragma unroll
    for (int j = 0; j < 4; ++j) acc[i][j] = f32x4{0.f, 0.f, 0.f, 0.f};

  const int ar0 = tid >> 2;
  const int ac0 = (((tid & 3) ^ ((ar0 >> 1) & 3))) * 8;
  const __hip_bfloat16* Abase0 = A + (size_t)(m0 + ar0) * K + ac0;
  const __hip_bfloat16* Abase1 = A + (size_t)(m0 + 64 + ar0) * K + ac0;
  const __hip_bfloat16* Wbase0 = W + (size_t)(n0 + ar0) * K + ac0;
  const __hip_bfloat16* Wbase1 = W + (size_t)(n0 + 64 + ar0) * K + ac0;

  auto stage = [&](int buf, int k0) {
    gload_lds16(Abase0 + k0, &smA[buf][wave * 512]);
    gload_lds16(Abase1 + k0, &smA[buf][2048 + wave * 512]);
    gload_lds16(Wbase0 + k0, &smB[buf][wave * 512]);
    gload_lds16(Wbase1 + k0, &smB[buf][2048 + wave * 512]);
  };

  const int rA = lane & 15;
  const int fq = lane >> 4;
  const int nk = K / TILE_K;

  stage(0, 0);

  int cur = 0;
  for (int t = 0; t < nk; ++t) {
    asm volatile("s_waitcnt vmcnt(0)" ::: "memory");
    asm volatile("s_barrier" ::: "memory");
    if (t + 1 < nk) stage(cur ^ 1, (t + 1) * TILE_K);

    s16x8 af[4], bfr[4];
#pragma unroll
    for (int mi = 0; mi < 4; ++mi) {
      const int row = wr * 64 + mi * 16 + rA;
      const int g = fq ^ ((row >> 1) & 3);
      af[mi] = *(const s16x8*)&smA[cur][row * TILE_K + g * 8];
    }
#pragma unroll
    for (int ni = 0; ni < 4; ++ni) {
      const int row = wc * 64 + ni * 16 + rA;
      const int g = fq ^ ((row >> 1) & 3);
      bfr[ni] = *(const s16x8*)&smB[cur][row * TILE_K + g * 8];
    }
#pragma unroll
    for (int mi = 0; mi < 4; ++mi)
#pragma unroll
      for (int ni = 0; ni < 4; ++ni)
        acc[mi][ni] = __builtin_amdgcn_mfma_f32_16x16x32_bf16(
            af[mi], bfr[ni], acc[mi][ni], 0, 0, 0);
    cur ^= 1;
  }

  const int crow = (lane >> 4) * 4;
  const int ccol = lane & 15;
#pragma unroll
  for (int mi = 0; mi < 4; ++mi) {
#pragma unroll
    for (int ni = 0; ni < 4; ++ni) {
      const int col = n0 + wc * 64 + ni * 16 + ccol;
      const float bv = bias[col];
#pragma unroll
      for (int j = 0; j < 4; ++j) {
        const int row = m0 + wr * 64 + mi * 16 + crow + j;
        float v = acc[mi][ni][j] + bv;
        const size_t o = (size_t)row * N + col;
        if (EPI == 0) {
          outb[o] = __float2bfloat16(v);
        } else if (EPI == 1) {
          outb[o] = __float2bfloat16(gelu_f(v));
        } else {
          outf[o] = resid[o] + v;
        }
      }
    }
  }
}

// ---------------- 64x128 GEMM (proj / FC2, N=768): doubles grid to 768 ----------------
// Same verified counted-vmcnt + XOR swizzle math; TILE_M=64 -> 12 waves/CU
// instead of 6 for the skinny-N GEMMs (they were 1.5 blocks/CU latency-bound).
// LDS 24KB. 4 waves: wr=wave>>1 (32-row half), wc=wave&1 (64-col half); acc[2][4].
template <int EPI>
__global__ __launch_bounds__(256) void gemm_bt64(
    const __hip_bfloat16* __restrict__ A, const __hip_bfloat16* __restrict__ W,
    const float* __restrict__ bias, const float* __restrict__ resid,
    __hip_bfloat16* __restrict__ outb, float* __restrict__ outf,
    int M, int N, int K) {
  __shared__ __hip_bfloat16 smA[2][64 * TILE_K];
  __shared__ __hip_bfloat16 smB[2][128 * TILE_K];
  const int tid = threadIdx.x;
  const int lane = tid & 63;
  const int wave = tid >> 6;

  const int nbx = gridDim.x;
  const int nwg = nbx * gridDim.y;
  int bid = blockIdx.y * nbx + blockIdx.x;
  if ((nwg & 7) == 0) bid = (bid & 7) * (nwg >> 3) + (bid >> 3);
  const int m0 = (bid / nbx) * 64;
  const int n0 = (bid % nbx) * 128;
  const int wr = wave >> 1, wc = wave & 1;

  f32x4 acc[2][4];
#pragma unroll
  for (int i = 0; i < 2; ++i)
#pragma unroll
    for (int j = 0; j < 4; ++j) acc[i][j] = f32x4{0.f, 0.f, 0.f, 0.f};

  // staging: A = 256 granules (1/thread), B = 512 granules (2/thread).
  // granule (row = tid>>2, g = tid&3); source col granule = g ^ ((row>>1)&3)
  const int ar = tid >> 2;
  const int ac = (((tid & 3) ^ ((ar >> 1) & 3))) * 8;
  const __hip_bfloat16* Abase  = A + (size_t)(m0 + ar) * K + ac;
  const __hip_bfloat16* Wbase0 = W + (size_t)(n0 + ar) * K + ac;
  const __hip_bfloat16* Wbase1 = W + (size_t)(n0 + 64 + ar) * K + ac;

  auto stage = [&](int buf, int k0) {
    gload_lds16(Abase + k0, &smA[buf][wave * 512]);
    gload_lds16(Wbase0 + k0, &smB[buf][wave * 512]);
    gload_lds16(Wbase1 + k0, &smB[buf][2048 + wave * 512]);
  };

  const int rA = lane & 15;
  const int fq = lane >> 4;
  const int nk = K / TILE_K;

  stage(0, 0);

  int cur = 0;
  for (int t = 0; t < nk; ++t) {
    asm volatile("s_waitcnt vmcnt(0)" ::: "memory");
    asm volatile("s_barrier" ::: "memory");
    if (t + 1 < nk) stage(cur ^ 1, (t + 1) * TILE_K);

    s16x8 af[2], bfr[4];
#pragma unroll
    for (int mi = 0; mi < 2; ++mi) {
      const int row = wr * 32 + mi * 16 + rA;
      const int g = fq ^ ((row >> 1) & 3);
      af[mi] = *(const s16x8*)&smA[cur][row * TILE_K + g * 8];
    }
#pragma unroll
    for (int ni = 0; ni < 4; ++ni) {
      const int row = wc * 64 + ni * 16 + rA;
      const int g = fq ^ ((row >> 1) & 3);
      bfr[ni] = *(const s16x8*)&smB[cur][row * TILE_K + g * 8];
    }
#pragma unroll
    for (int mi = 0; mi < 2; ++mi)
#pragma unroll
      for (int ni = 0; ni < 4; ++ni)
        acc[mi][ni] = __builtin_amdgcn_mfma_f32_16x16x32_bf16(
            af[mi], bfr[ni], acc[mi][ni], 0, 0, 0);
    cur ^= 1;
  }

  const int crow = (lane >> 4) * 4;
  const int ccol = lane & 15;
#pragma unroll
  for (int mi = 0; mi < 2; ++mi) {
#pragma unroll
    for (int ni = 0; ni < 4; ++ni) {
      const int col = n0 + wc * 64 + ni * 16 + ccol;
      const float bv = bias[col];
#pragma unroll
      for (int j = 0; j < 4; ++j) {
        const int row = m0 + wr * 32 + mi * 16 + crow + j;
        float v = acc[mi][ni][j] + bv;
        const size_t o = (size_t)row * N + col;
        if (EPI == 0) {
          outb[o] = __float2bfloat16(v);
        } else if (EPI == 1) {
          outb[o] = __float2bfloat16(gelu_f(v));
        } else {
          outf[o] = resid[o] + v;
        }
      }
    }
  }
}

// ---------------- MFMA causal flash attention, v4 + packed P ----------------
#define AP 72

__global__ __launch_bounds__(256) void attn_mfma(
    const __hip_bfloat16* __restrict__ qkv, __hip_bfloat16* __restrict__ y,
    int T) {
  __shared__ __hip_bfloat16 ks[2][64 * AP];
  __shared__ __hip_bfloat16 vt[2][64 * AP];
  __shared__ __hip_bfloat16 ps[4][16 * AP];
  const int tid = threadIdx.x;
  const int lane = tid & 63;
  const int wave = tid >> 6;
  const int b = blockIdx.y / N_HEADS, h = blockIdx.y % N_HEADS;
  const int nq = T / 64;
  const int qa0 = blockIdx.x * 64;
  const int qb0 = (nq - 1 - blockIdx.x) * 64;
  const size_t ldq = 3 * N_EMBD;
  const __hip_bfloat16* qb_ = qkv + (size_t)b * T * ldq + h * HEAD_DIM;
  const __hip_bfloat16* kb = qb_ + N_EMBD;
  const __hip_bfloat16* vb = qb_ + 2 * N_EMBD;

  const int fr = lane & 15;
  const int fo = (lane >> 4) * 8;
  const int crow = (lane >> 4) * 4;

  const float qs = 0.125f * 1.44269504f;
  auto loadq = [&](int qrow, int o) -> s16x8 {
    s16x8 v = *(const s16x8*)(qb_ + (size_t)qrow * ldq + o);
    s16x8 r;
#pragma unroll
    for (int i = 0; i < 8; ++i) {
      float f = bf2f((unsigned short)v[i]) * qs;
      __hip_bfloat16 hb = __float2bfloat16(f);
      r[i] = *reinterpret_cast<short*>(&hb);
    }
    return r;
  };
  s16x8 qfa0 = loadq(qa0 + wave * 16 + fr, fo);
  s16x8 qfa1 = loadq(qa0 + wave * 16 + fr, fo + 32);
  s16x8 qfb0 = loadq(qb0 + wave * 16 + fr, fo);
  s16x8 qfb1 = loadq(qb0 + wave * 16 + fr, fo + 32);

  f32x4 oa[4], ob[4];
#pragma unroll
  for (int j = 0; j < 4; ++j) {
    oa[j] = f32x4{0.f, 0.f, 0.f, 0.f};
    ob[j] = f32x4{0.f, 0.f, 0.f, 0.f};
  }
  float m_a = -1e30f, l_a = 0.f, m_b = -1e30f, l_b = 0.f;

  s16x8 kr0, kr1, vr0, vr1;
  const int krow0 = tid >> 3;
  const int kcol = (tid & 7) * 8;
  const int vkey = 2 * (lane & 31);
  const int vd0 = wave * 16 + (lane >> 5) * 8;

  auto loadKV = [&](int kt) {
    kr0 = *(const s16x8*)(kb + (size_t)(kt + krow0) * ldq + kcol);
    kr1 = *(const s16x8*)(kb + (size_t)(kt + 32 + krow0) * ldq + kcol);
    vr0 = *(const s16x8*)(vb + (size_t)(kt + vkey) * ldq + vd0);
    vr1 = *(const s16x8*)(vb + (size_t)(kt + vkey + 1) * ldq + vd0);
  };
  auto writeKV = [&](int bufi) {
    *(s16x8*)&ks[bufi][krow0 * AP + kcol] = kr0;
    *(s16x8*)&ks[bufi][(32 + krow0) * AP + kcol] = kr1;
#pragma unroll
    for (int i = 0; i < 8; ++i) {
      unsigned u = (unsigned short)vr0[i] | ((unsigned)(unsigned short)vr1[i] << 16);
      *(unsigned*)&vt[bufi][(vd0 + i) * AP + vkey] = u;
    }
  };

  auto process = [&](int bufi, const s16x8& q0f, const s16x8& q1f,
                     f32x4 (&o)[4], float& m_, float& l_, int tq0, bool diag,
                     int kt) {
    f32x4 sv[4];
#pragma unroll
    for (int sub = 0; sub < 4; ++sub) {
      s16x8 k0 = *(const s16x8*)&ks[bufi][(sub * 16 + fr) * AP + fo];
      s16x8 k1 = *(const s16x8*)&ks[bufi][(sub * 16 + fr) * AP + 32 + fo];
      f32x4 acc = f32x4{0.f, 0.f, 0.f, 0.f};
      acc = __builtin_amdgcn_mfma_f32_16x16x32_bf16(k0, q0f, acc, 0, 0, 0);
      acc = __builtin_amdgcn_mfma_f32_16x16x32_bf16(k1, q1f, acc, 0, 0, 0);
      sv[sub] = acc;
    }
    const int qg = tq0 + wave * 16 + fr;
    if (diag) {
#pragma unroll
      for (int sub = 0; sub < 4; ++sub)
#pragma unroll
        for (int j = 0; j < 4; ++j)
          if (kt + sub * 16 + crow + j > qg) sv[sub][j] = -1e30f;
    }
    float t = fmaxf(fmaxf(sv[0][0], sv[0][1]), fmaxf(sv[0][2], sv[0][3]));
#pragma unroll
    for (int sub = 1; sub < 4; ++sub)
      t = fmaxf(t, fmaxf(fmaxf(sv[sub][0], sv[sub][1]),
                         fmaxf(sv[sub][2], sv[sub][3])));
    t = fmaxf(t, __shfl_xor(t, 16));
    t = fmaxf(t, __shfl_xor(t, 32));
    const bool resc = t > m_ + 8.0f;
    const float corr = resc ? exp2f(m_ - t) : 1.0f;
    if (resc) m_ = t;
    float rs = 0.f;
#pragma unroll
    for (int sub = 0; sub < 4; ++sub) {
      float p0 = exp2f(sv[sub][0] - m_);
      float p1 = exp2f(sv[sub][1] - m_);
      float p2 = exp2f(sv[sub][2] - m_);
      float p3 = exp2f(sv[sub][3] - m_);
      rs += p0 + p1 + p2 + p3;
      __hip_bfloat16 b0 = __float2bfloat16(p0), b1 = __float2bfloat16(p1);
      __hip_bfloat16 b2 = __float2bfloat16(p2), b3 = __float2bfloat16(p3);
      unsigned u01 = (unsigned)*(unsigned short*)&b0 |
                     ((unsigned)*(unsigned short*)&b1 << 16);
      unsigned u23 = (unsigned)*(unsigned short*)&b2 |
                     ((unsigned)*(unsigned short*)&b3 << 16);
      uint2 u; u.x = u01; u.y = u23;
      *(uint2*)&ps[wave][fr * AP + sub * 16 + crow] = u;
    }
    rs += __shfl_xor(rs, 16);
    rs += __shfl_xor(rs, 32);
    l_ = l_ * corr + rs;
    if (__any(resc)) {
#pragma unroll
      for (int j = 0; j < 4; ++j) {
        const float cj = __shfl(corr, (lane & 0x30) | (crow + j));
#pragma unroll
        for (int ds = 0; ds < 4; ++ds) o[ds][j] *= cj;
      }
    }
    s16x8 pf0 = *(const s16x8*)&ps[wave][fr * AP + fo];
    s16x8 pf1 = *(const s16x8*)&ps[wave][fr * AP + 32 + fo];
#pragma unroll
    for (int ds = 0; ds < 4; ++ds) {
      s16x8 v0 = *(const s16x8*)&vt[bufi][(ds * 16 + fr) * AP + fo];
      s16x8 v1 = *(const s16x8*)&vt[bufi][(ds * 16 + fr) * AP + 32 + fo];
      o[ds] = __builtin_amdgcn_mfma_f32_16x16x32_bf16(pf0, v0, o[ds], 0, 0, 0);
      o[ds] = __builtin_amdgcn_mfma_f32_16x16x32_bf16(pf1, v1, o[ds], 0, 0, 0);
    }
  };

  loadKV(0);
  writeKV(0);
  __syncthreads();
  int cur = 0;
  for (int kt = 0; kt <= qb0; kt += 64) {
    const bool hasnext = (kt + 64 <= qb0);
    if (hasnext) loadKV(kt + 64);
    if (kt <= qa0)
      process(cur, qfa0, qfa1, oa, m_a, l_a, qa0, kt == qa0, kt);
    process(cur, qfb0, qfb1, ob, m_b, l_b, qb0, kt == qb0, kt);
    if (hasnext) writeKV(cur ^ 1);
    __syncthreads();
    cur ^= 1;
  }

#pragma unroll
  for (int j = 0; j < 4; ++j) {
    const float la_j = __shfl(l_a, (lane & 0x30) | (crow + j));
    const float lb_j = __shfl(l_b, (lane & 0x30) | (crow + j));
    const float inva = 1.0f / la_j;
    const float invb = 1.0f / lb_j;
    __hip_bfloat16* ya =
        y + (size_t)(b * T + qa0 + wave * 16 + crow + j) * N_EMBD + h * HEAD_DIM;
    __hip_bfloat16* yb =
        y + (size_t)(b * T + qb0 + wave * 16 + crow + j) * N_EMBD + h * HEAD_DIM;
#pragma unroll
    for (int ds = 0; ds < 4; ++ds) {
      ya[ds * 16 + fr] = __float2bfloat16(oa[ds][j] * inva);
      yb[ds * 16 + fr] = __float2bfloat16(ob[ds][j] * invb);
    }
  }
}

// ---------------- launch ----------------
extern "C" void kernel_launch(void* const* d_in, const int* in_sizes, int n_in,
                              void* d_out, int out_size, void* d_ws,
                              size_t ws_size, hipStream_t stream) {
  const int B = 4, T = 2048, C = N_EMBD;
  const int M = B * T;  // 8192

  const float* x      = (const float*)d_in[0];
  const float* ln1_g  = (const float*)d_in[1];
  const float* ln1_b  = (const float*)d_in[2];
  const float* attn_w = (const float*)d_in[3];
  const float* attn_b = (const float*)d_in[4];
  const float* proj_w = (const float*)d_in[5];
  const float* proj_b = (const float*)d_in[6];
  const float* ln2_g  = (const float*)d_in[7];
  const float* ln2_b  = (const float*)d_in[8];
  const float* fc_w   = (const float*)d_in[9];
  const float* fc_b   = (const float*)d_in[10];
  const float* fc2_w  = (const float*)d_in[11];
  const float* fc2_b  = (const float*)d_in[12];
  float* out = (float*)d_out;

  char* p = (char*)d_ws;
  size_t off = 0;
  auto take = [&](size_t bytes) -> void* {
    void* q = p + off;
    off += (bytes + 1023) & ~(size_t)1023;
    return q;
  };

  __hip_bfloat16* wqkv  = (__hip_bfloat16*)take((size_t)3 * C * C * 2);
  __hip_bfloat16* wproj = (__hip_bfloat16*)take((size_t)C * C * 2);
  __hip_bfloat16* wfc   = (__hip_bfloat16*)take((size_t)4 * C * C * 2);
  __hip_bfloat16* wfc2  = (__hip_bfloat16*)take((size_t)4 * C * C * 2);
  __hip_bfloat16* hbuf  = (__hip_bfloat16*)take((size_t)M * C * 2);
  __hip_bfloat16* big   = (__hip_bfloat16*)take((size_t)M * 4 * C * 2);
  __hip_bfloat16* ybuf  = (__hip_bfloat16*)take((size_t)M * C * 2);
  float*          x1    = (float*)take((size_t)M * C * 4);

  {
    const int n0 = 3 * C * C, n1 = C * C, n2 = 4 * C * C, n3 = 4 * C * C;
    const int ntot = n0 + n1 + n2 + n3;
    cvt4_kernel<<<(ntot + 255) / 256, 256, 0, stream>>>(
        attn_w, wqkv, proj_w, wproj, fc_w, wfc, fc2_w, wfc2, n0, n1, n2, n3);
  }

  ln_kernel<<<M, 256, 0, stream>>>(x, ln1_g, ln1_b, hbuf);
  gemm_bt<0><<<dim3(3 * C / TILE_N, M / TILE_M), 256, 0, stream>>>(
      hbuf, wqkv, attn_b, nullptr, big, nullptr, M, 3 * C, C);
  attn_mfma<<<dim3(T / 128, B * N_HEADS), 256, 0, stream>>>(big, ybuf, T);
  // proj: 64x128 tiles -> grid 6x128 = 768 blocks (was 384)
  gemm_bt64<2><<<dim3(C / 128, M / 64), 256, 0, stream>>>(
      ybuf, wproj, proj_b, x, nullptr, x1, M, C, C);
  ln_kernel<<<M, 256, 0, stream>>>(x1, ln2_g, ln2_b, hbuf);
  gemm_bt<1><<<dim3(4 * C / TILE_N, M / TILE_M), 256, 0, stream>>>(
      hbuf, wfc, fc_b, nullptr, big, nullptr, M, 4 * C, C);
  // FC2: 64x128 tiles, K=3072 -> grid 768 blocks
  gemm_bt64<2><<<dim3(C / 128, M / 64), 256, 0, stream>>>(
      big, wfc2, fc2_b, x1, nullptr, out, M, C, 4 * C);
}

// Round 18
// 294.933 us; speedup vs baseline: 1.0387x; 1.0149x over previous
//
#include <hip/hip_runtime.h>
#include <hip/hip_bf16.h>

#define N_EMBD 768
#define N_HEADS 12
#define HEAD_DIM 64

typedef __attribute__((ext_vector_type(4))) float f32x4;
typedef __attribute__((ext_vector_type(8))) short s16x8;

__device__ __forceinline__ float bf2f(unsigned short u) {
  union { unsigned int i; float f; } z;
  z.i = ((unsigned int)u) << 16;
  return z.f;
}

__device__ __forceinline__ void gload_lds16(const void* g, void* l) {
  __builtin_amdgcn_global_load_lds(
      (const __attribute__((address_space(1))) void*)g,
      (__attribute__((address_space(3))) void*)l, 16, 0, 0);
}

__device__ __forceinline__ float gelu_f(float x) {
  const float c = 0.7978845608028654f;
  float u = c * (x + 0.044715f * x * x * x);
  float t = 1.0f - 2.0f / (__expf(2.0f * u) + 1.0f);
  return 0.5f * x * (1.0f + t);
}

// ---------------- weight fp32 -> bf16 (all four in one launch) ----------------
__global__ void cvt4_kernel(const float* __restrict__ s0, __hip_bfloat16* d0,
                            const float* __restrict__ s1, __hip_bfloat16* d1,
                            const float* __restrict__ s2, __hip_bfloat16* d2,
                            const float* __restrict__ s3, __hip_bfloat16* d3,
                            int n0, int n1, int n2, int n3) {
  int i = blockIdx.x * 256 + threadIdx.x;
  if (i < n0) { d0[i] = __float2bfloat16(s0[i]); return; }
  i -= n0;
  if (i < n1) { d1[i] = __float2bfloat16(s1[i]); return; }
  i -= n1;
  if (i < n2) { d2[i] = __float2bfloat16(s2[i]); return; }
  i -= n2;
  if (i < n3) d3[i] = __float2bfloat16(s3[i]);
}

// ---------------- fused LayerNorm: fp32 in -> bf16 out ----------------
__global__ __launch_bounds__(256) void ln_kernel(
    const float* __restrict__ x, const float* __restrict__ g,
    const float* __restrict__ b, __hip_bfloat16* __restrict__ out) {
  __shared__ float red[8];
  const int row = blockIdx.x;
  const int tid = threadIdx.x;
  const float* xr = x + (size_t)row * N_EMBD;
  float v0 = xr[tid], v1 = xr[tid + 256], v2 = xr[tid + 512];
  float s = v0 + v1 + v2;
#pragma unroll
  for (int m = 32; m >= 1; m >>= 1) s += __shfl_xor(s, m);
  if ((tid & 63) == 0) red[tid >> 6] = s;
  __syncthreads();
  float mu = (red[0] + red[1] + red[2] + red[3]) * (1.0f / 768.0f);
  float d0 = v0 - mu, d1 = v1 - mu, d2 = v2 - mu;
  float ss = d0 * d0 + d1 * d1 + d2 * d2;
  __syncthreads();
#pragma unroll
  for (int m = 32; m >= 1; m >>= 1) ss += __shfl_xor(ss, m);
  if ((tid & 63) == 0) red[4 + (tid >> 6)] = ss;
  __syncthreads();
  float var = (red[4] + red[5] + red[6] + red[7]) * (1.0f / 768.0f);
  float rstd = rsqrtf(var + 1e-5f);
  __hip_bfloat16* orow = out + (size_t)row * N_EMBD;
  orow[tid]       = __float2bfloat16(d0 * rstd * g[tid]       + b[tid]);
  orow[tid + 256] = __float2bfloat16(d1 * rstd * g[tid + 256] + b[tid + 256]);
  orow[tid + 512] = __float2bfloat16(d2 * rstd * g[tid + 512] + b[tid + 512]);
}

// ---------------- 128x128 GEMM, counted-vmcnt + XOR swizzle + 2D XCD regions ----------------
// XCD remap: bid grid (nby rows x nbx cols) split into 4x2 = 8 rectangular
// regions, one per XCD (region = (nby/4) x (nbx/2) tiles). Per-XCD operand
// footprint becomes L2-resident (FC: A 3.1MB + W 2.4MB < 4MB L2) so staged
// loads hit L2 (~200cy) instead of HBM (~900cy) -> shorter vmcnt stalls.
#define TILE_M 128
#define TILE_N 128
#define TILE_K 32

template <int EPI>
__global__ __launch_bounds__(256) void gemm_bt(
    const __hip_bfloat16* __restrict__ A, const __hip_bfloat16* __restrict__ W,
    const float* __restrict__ bias, const float* __restrict__ resid,
    __hip_bfloat16* __restrict__ outb, float* __restrict__ outf,
    int M, int N, int K) {
  __shared__ __hip_bfloat16 smA[2][TILE_M * TILE_K];
  __shared__ __hip_bfloat16 smB[2][TILE_N * TILE_K];
  const int tid = threadIdx.x;
  const int lane = tid & 63;
  const int wave = tid >> 6;

  const int nbx = gridDim.x;   // col tiles
  const int nby = gridDim.y;   // row tiles
  int brow, bcol;
  if ((nby & 3) == 0 && (nbx & 1) == 0) {
    const int b0 = blockIdx.y * nbx + blockIdx.x;
    const int xcd = b0 & 7;
    const int idx = b0 >> 3;
    const int RW = nbx >> 1;          // region width
    brow = (xcd >> 1) * (nby >> 2) + idx / RW;
    bcol = (xcd & 1) * RW + idx % RW;
  } else {
    brow = blockIdx.y; bcol = blockIdx.x;
  }
  const int m0 = brow * TILE_M;
  const int n0 = bcol * TILE_N;
  const int wr = wave >> 1, wc = wave & 1;

  f32x4 acc[4][4];
#pragma unroll
  for (int i = 0; i < 4; ++i)
#pragma unroll
    for (int j = 0; j < 4; ++j) acc[i][j] = f32x4{0.f, 0.f, 0.f, 0.f};

  const int ar0 = tid >> 2;
  const int ac0 = (((tid & 3) ^ ((ar0 >> 1) & 3))) * 8;
  const __hip_bfloat16* Abase0 = A + (size_t)(m0 + ar0) * K + ac0;
  const __hip_bfloat16* Abase1 = A + (size_t)(m0 + 64 + ar0) * K + ac0;
  const __hip_bfloat16* Wbase0 = W + (size_t)(n0 + ar0) * K + ac0;
  const __hip_bfloat16* Wbase1 = W + (size_t)(n0 + 64 + ar0) * K + ac0;

  auto stage = [&](int buf, int k0) {
    gload_lds16(Abase0 + k0, &smA[buf][wave * 512]);
    gload_lds16(Abase1 + k0, &smA[buf][2048 + wave * 512]);
    gload_lds16(Wbase0 + k0, &smB[buf][wave * 512]);
    gload_lds16(Wbase1 + k0, &smB[buf][2048 + wave * 512]);
  };

  const int rA = lane & 15;
  const int fq = lane >> 4;
  const int nk = K / TILE_K;

  stage(0, 0);

  int cur = 0;
  for (int t = 0; t < nk; ++t) {
    asm volatile("s_waitcnt vmcnt(0)" ::: "memory");
    asm volatile("s_barrier" ::: "memory");
    if (t + 1 < nk) stage(cur ^ 1, (t + 1) * TILE_K);

    s16x8 af[4], bfr[4];
#pragma unroll
    for (int mi = 0; mi < 4; ++mi) {
      const int row = wr * 64 + mi * 16 + rA;
      const int g = fq ^ ((row >> 1) & 3);
      af[mi] = *(const s16x8*)&smA[cur][row * TILE_K + g * 8];
    }
#pragma unroll
    for (int ni = 0; ni < 4; ++ni) {
      const int row = wc * 64 + ni * 16 + rA;
      const int g = fq ^ ((row >> 1) & 3);
      bfr[ni] = *(const s16x8*)&smB[cur][row * TILE_K + g * 8];
    }
#pragma unroll
    for (int mi = 0; mi < 4; ++mi)
#pragma unroll
      for (int ni = 0; ni < 4; ++ni)
        acc[mi][ni] = __builtin_amdgcn_mfma_f32_16x16x32_bf16(
            af[mi], bfr[ni], acc[mi][ni], 0, 0, 0);
    cur ^= 1;
  }

  const int crow = (lane >> 4) * 4;
  const int ccol = lane & 15;
#pragma unroll
  for (int mi = 0; mi < 4; ++mi) {
#pragma unroll
    for (int ni = 0; ni < 4; ++ni) {
      const int col = n0 + wc * 64 + ni * 16 + ccol;
      const float bv = bias[col];
#pragma unroll
      for (int j = 0; j < 4; ++j) {
        const int row = m0 + wr * 64 + mi * 16 + crow + j;
        float v = acc[mi][ni][j] + bv;
        const size_t o = (size_t)row * N + col;
        if (EPI == 0) {
          outb[o] = __float2bfloat16(v);
        } else if (EPI == 1) {
          outb[o] = __float2bfloat16(gelu_f(v));
        } else {
          outf[o] = resid[o] + v;
        }
      }
    }
  }
}

// ---------------- MFMA causal flash attention, v4 + packed P + bh-chunked XCD swizzle ----------------
// Swizzle (R7-proven for FETCH 123->18.5MB): each XCD owns 96 consecutive
// virt ids = 6 bh's x 16 q-tile-pairs -> K/V footprint 3MB, L2-resident.
#define AP 72

__global__ __launch_bounds__(256) void attn_mfma(
    const __hip_bfloat16* __restrict__ qkv, __hip_bfloat16* __restrict__ y,
    int T) {
  __shared__ __hip_bfloat16 ks[2][64 * AP];
  __shared__ __hip_bfloat16 vt[2][64 * AP];
  __shared__ __hip_bfloat16 ps[4][16 * AP];
  const int tid = threadIdx.x;
  const int lane = tid & 63;
  const int wave = tid >> 6;

  // chunked XCD swizzle: virt = (orig&7)*(nwg/8) + orig>>3; bh = virt/nbx
  const int nbx = gridDim.x;  // 16
  const int nwg = nbx * gridDim.y;
  int bid = blockIdx.y * nbx + blockIdx.x;
  if ((nwg & 7) == 0) bid = (bid & 7) * (nwg >> 3) + (bid >> 3);
  const int bx = bid % nbx;
  const int bh = bid / nbx;
  const int b = bh / N_HEADS, h = bh % N_HEADS;

  const int nq = T / 64;
  const int qa0 = bx * 64;
  const int qb0 = (nq - 1 - bx) * 64;
  const size_t ldq = 3 * N_EMBD;
  const __hip_bfloat16* qb_ = qkv + (size_t)b * T * ldq + h * HEAD_DIM;
  const __hip_bfloat16* kb = qb_ + N_EMBD;
  const __hip_bfloat16* vb = qb_ + 2 * N_EMBD;

  const int fr = lane & 15;
  const int fo = (lane >> 4) * 8;
  const int crow = (lane >> 4) * 4;

  const float qs = 0.125f * 1.44269504f;
  auto loadq = [&](int qrow, int o) -> s16x8 {
    s16x8 v = *(const s16x8*)(qb_ + (size_t)qrow * ldq + o);
    s16x8 r;
#pragma unroll
    for (int i = 0; i < 8; ++i) {
      float f = bf2f((unsigned short)v[i]) * qs;
      __hip_bfloat16 hb = __float2bfloat16(f);
      r[i] = *reinterpret_cast<short*>(&hb);
    }
    return r;
  };
  s16x8 qfa0 = loadq(qa0 + wave * 16 + fr, fo);
  s16x8 qfa1 = loadq(qa0 + wave * 16 + fr, fo + 32);
  s16x8 qfb0 = loadq(qb0 + wave * 16 + fr, fo);
  s16x8 qfb1 = loadq(qb0 + wave * 16 + fr, fo + 32);

  f32x4 oa[4], ob[4];
#pragma unroll
  for (int j = 0; j < 4; ++j) {
    oa[j] = f32x4{0.f, 0.f, 0.f, 0.f};
    ob[j] = f32x4{0.f, 0.f, 0.f, 0.f};
  }
  float m_a = -1e30f, l_a = 0.f, m_b = -1e30f, l_b = 0.f;

  s16x8 kr0, kr1, vr0, vr1;
  const int krow0 = tid >> 3;
  const int kcol = (tid & 7) * 8;
  const int vkey = 2 * (lane & 31);
  const int vd0 = wave * 16 + (lane >> 5) * 8;

  auto loadKV = [&](int kt) {
    kr0 = *(const s16x8*)(kb + (size_t)(kt + krow0) * ldq + kcol);
    kr1 = *(const s16x8*)(kb + (size_t)(kt + 32 + krow0) * ldq + kcol);
    vr0 = *(const s16x8*)(vb + (size_t)(kt + vkey) * ldq + vd0);
    vr1 = *(const s16x8*)(vb + (size_t)(kt + vkey + 1) * ldq + vd0);
  };
  auto writeKV = [&](int bufi) {
    *(s16x8*)&ks[bufi][krow0 * AP + kcol] = kr0;
    *(s16x8*)&ks[bufi][(32 + krow0) * AP + kcol] = kr1;
#pragma unroll
    for (int i = 0; i < 8; ++i) {
      unsigned u = (unsigned short)vr0[i] | ((unsigned)(unsigned short)vr1[i] << 16);
      *(unsigned*)&vt[bufi][(vd0 + i) * AP + vkey] = u;
    }
  };

  auto process = [&](int bufi, const s16x8& q0f, const s16x8& q1f,
                     f32x4 (&o)[4], float& m_, float& l_, int tq0, bool diag,
                     int kt) {
    f32x4 sv[4];
#pragma unroll
    for (int sub = 0; sub < 4; ++sub) {
      s16x8 k0 = *(const s16x8*)&ks[bufi][(sub * 16 + fr) * AP + fo];
      s16x8 k1 = *(const s16x8*)&ks[bufi][(sub * 16 + fr) * AP + 32 + fo];
      f32x4 acc = f32x4{0.f, 0.f, 0.f, 0.f};
      acc = __builtin_amdgcn_mfma_f32_16x16x32_bf16(k0, q0f, acc, 0, 0, 0);
      acc = __builtin_amdgcn_mfma_f32_16x16x32_bf16(k1, q1f, acc, 0, 0, 0);
      sv[sub] = acc;
    }
    const int qg = tq0 + wave * 16 + fr;
    if (diag) {
#pragma unroll
      for (int sub = 0; sub < 4; ++sub)
#pragma unroll
        for (int j = 0; j < 4; ++j)
          if (kt + sub * 16 + crow + j > qg) sv[sub][j] = -1e30f;
    }
    float t = fmaxf(fmaxf(sv[0][0], sv[0][1]), fmaxf(sv[0][2], sv[0][3]));
#pragma unroll
    for (int sub = 1; sub < 4; ++sub)
      t = fmaxf(t, fmaxf(fmaxf(sv[sub][0], sv[sub][1]),
                         fmaxf(sv[sub][2], sv[sub][3])));
    t = fmaxf(t, __shfl_xor(t, 16));
    t = fmaxf(t, __shfl_xor(t, 32));
    const bool resc = t > m_ + 8.0f;
    const float corr = resc ? exp2f(m_ - t) : 1.0f;
    if (resc) m_ = t;
    float rs = 0.f;
#pragma unroll
    for (int sub = 0; sub < 4; ++sub) {
      float p0 = exp2f(sv[sub][0] - m_);
      float p1 = exp2f(sv[sub][1] - m_);
      float p2 = exp2f(sv[sub][2] - m_);
      float p3 = exp2f(sv[sub][3] - m_);
      rs += p0 + p1 + p2 + p3;
      __hip_bfloat16 b0 = __float2bfloat16(p0), b1 = __float2bfloat16(p1);
      __hip_bfloat16 b2 = __float2bfloat16(p2), b3 = __float2bfloat16(p3);
      unsigned u01 = (unsigned)*(unsigned short*)&b0 |
                     ((unsigned)*(unsigned short*)&b1 << 16);
      unsigned u23 = (unsigned)*(unsigned short*)&b2 |
                     ((unsigned)*(unsigned short*)&b3 << 16);
      uint2 u; u.x = u01; u.y = u23;
      *(uint2*)&ps[wave][fr * AP + sub * 16 + crow] = u;
    }
    rs += __shfl_xor(rs, 16);
    rs += __shfl_xor(rs, 32);
    l_ = l_ * corr + rs;
    if (__any(resc)) {
#pragma unroll
      for (int j = 0; j < 4; ++j) {
        const float cj = __shfl(corr, (lane & 0x30) | (crow + j));
#pragma unroll
        for (int ds = 0; ds < 4; ++ds) o[ds][j] *= cj;
      }
    }
    s16x8 pf0 = *(const s16x8*)&ps[wave][fr * AP + fo];
    s16x8 pf1 = *(const s16x8*)&ps[wave][fr * AP + 32 + fo];
#pragma unroll
    for (int ds = 0; ds < 4; ++ds) {
      s16x8 v0 = *(const s16x8*)&vt[bufi][(ds * 16 + fr) * AP + fo];
      s16x8 v1 = *(const s16x8*)&vt[bufi][(ds * 16 + fr) * AP + 32 + fo];
      o[ds] = __builtin_amdgcn_mfma_f32_16x16x32_bf16(pf0, v0, o[ds], 0, 0, 0);
      o[ds] = __builtin_amdgcn_mfma_f32_16x16x32_bf16(pf1, v1, o[ds], 0, 0, 0);
    }
  };

  loadKV(0);
  writeKV(0);
  __syncthreads();
  int cur = 0;
  for (int kt = 0; kt <= qb0; kt += 64) {
    const bool hasnext = (kt + 64 <= qb0);
    if (hasnext) loadKV(kt + 64);
    if (kt <= qa0)
      process(cur, qfa0, qfa1, oa, m_a, l_a, qa0, kt == qa0, kt);
    process(cur, qfb0, qfb1, ob, m_b, l_b, qb0, kt == qb0, kt);
    if (hasnext) writeKV(cur ^ 1);
    __syncthreads();
    cur ^= 1;
  }

#pragma unroll
  for (int j = 0; j < 4; ++j) {
    const float la_j = __shfl(l_a, (lane & 0x30) | (crow + j));
    const float lb_j = __shfl(l_b, (lane & 0x30) | (crow + j));
    const float inva = 1.0f / la_j;
    const float invb = 1.0f / lb_j;
    __hip_bfloat16* ya =
        y + (size_t)(b * T + qa0 + wave * 16 + crow + j) * N_EMBD + h * HEAD_DIM;
    __hip_bfloat16* yb =
        y + (size_t)(b * T + qb0 + wave * 16 + crow + j) * N_EMBD + h * HEAD_DIM;
#pragma unroll
    for (int ds = 0; ds < 4; ++ds) {
      ya[ds * 16 + fr] = __float2bfloat16(oa[ds][j] * inva);
      yb[ds * 16 + fr] = __float2bfloat16(ob[ds][j] * invb);
    }
  }
}

// ---------------- launch ----------------
extern "C" void kernel_launch(void* const* d_in, const int* in_sizes, int n_in,
                              void* d_out, int out_size, void* d_ws,
                              size_t ws_size, hipStream_t stream) {
  const int B = 4, T = 2048, C = N_EMBD;
  const int M = B * T;  // 8192

  const float* x      = (const float*)d_in[0];
  const float* ln1_g  = (const float*)d_in[1];
  const float* ln1_b  = (const float*)d_in[2];
  const float* attn_w = (const float*)d_in[3];
  const float* attn_b = (const float*)d_in[4];
  const float* proj_w = (const float*)d_in[5];
  const float* proj_b = (const float*)d_in[6];
  const float* ln2_g  = (const float*)d_in[7];
  const float* ln2_b  = (const float*)d_in[8];
  const float* fc_w   = (const float*)d_in[9];
  const float* fc_b   = (const float*)d_in[10];
  const float* fc2_w  = (const float*)d_in[11];
  const float* fc2_b  = (const float*)d_in[12];
  float* out = (float*)d_out;

  char* p = (char*)d_ws;
  size_t off = 0;
  auto take = [&](size_t bytes) -> void* {
    void* q = p + off;
    off += (bytes + 1023) & ~(size_t)1023;
    return q;
  };

  __hip_bfloat16* wqkv  = (__hip_bfloat16*)take((size_t)3 * C * C * 2);
  __hip_bfloat16* wproj = (__hip_bfloat16*)take((size_t)C * C * 2);
  __hip_bfloat16* wfc   = (__hip_bfloat16*)take((size_t)4 * C * C * 2);
  __hip_bfloat16* wfc2  = (__hip_bfloat16*)take((size_t)4 * C * C * 2);
  __hip_bfloat16* hbuf  = (__hip_bfloat16*)take((size_t)M * C * 2);
  __hip_bfloat16* big   = (__hip_bfloat16*)take((size_t)M * 4 * C * 2);
  __hip_bfloat16* ybuf  = (__hip_bfloat16*)take((size_t)M * C * 2);
  float*          x1    = (float*)take((size_t)M * C * 4);

  {
    const int n0 = 3 * C * C, n1 = C * C, n2 = 4 * C * C, n3 = 4 * C * C;
    const int ntot = n0 + n1 + n2 + n3;
    cvt4_kernel<<<(ntot + 255) / 256, 256, 0, stream>>>(
        attn_w, wqkv, proj_w, wproj, fc_w, wfc, fc2_w, wfc2, n0, n1, n2, n3);
  }

  ln_kernel<<<M, 256, 0, stream>>>(x, ln1_g, ln1_b, hbuf);
  gemm_bt<0><<<dim3(3 * C / TILE_N, M / TILE_M), 256, 0, stream>>>(
      hbuf, wqkv, attn_b, nullptr, big, nullptr, M, 3 * C, C);
  attn_mfma<<<dim3(T / 128, B * N_HEADS), 256, 0, stream>>>(big, ybuf, T);
  gemm_bt<2><<<dim3(C / TILE_N, M / TILE_M), 256, 0, stream>>>(
      ybuf, wproj, proj_b, x, nullptr, x1, M, C, C);
  ln_kernel<<<M, 256, 0, stream>>>(x1, ln2_g, ln2_b, hbuf);
  gemm_bt<1><<<dim3(4 * C / TILE_N, M / TILE_M), 256, 0, stream>>>(
      hbuf, wfc, fc_b, nullptr, big, nullptr, M, 4 * C, C);
  gemm_bt<2><<<dim3(C / TILE_N, M / TILE_M), 256, 0, stream>>>(
      big, wfc2, fc2_b, x1, nullptr, out, M, C, 4 * C);
}

// Round 19
// 292.050 us; speedup vs baseline: 1.0490x; 1.0099x over previous
//
#include <hip/hip_runtime.h>
#include <hip/hip_bf16.h>

#define N_EMBD 768
#define N_HEADS 12
#define HEAD_DIM 64

typedef __attribute__((ext_vector_type(4))) float f32x4;
typedef __attribute__((ext_vector_type(8))) short s16x8;

__device__ __forceinline__ float bf2f(unsigned short u) {
  union { unsigned int i; float f; } z;
  z.i = ((unsigned int)u) << 16;
  return z.f;
}

__device__ __forceinline__ void gload_lds16(const void* g, void* l) {
  __builtin_amdgcn_global_load_lds(
      (const __attribute__((address_space(1))) void*)g,
      (__attribute__((address_space(3))) void*)l, 16, 0, 0);
}

__device__ __forceinline__ float gelu_f(float x) {
  const float c = 0.7978845608028654f;
  float u = c * (x + 0.044715f * x * x * x);
  float t = 1.0f - 2.0f / (__expf(2.0f * u) + 1.0f);
  return 0.5f * x * (1.0f + t);
}

// ---------------- weight fp32 -> bf16 (all four in one launch) ----------------
__global__ void cvt4_kernel(const float* __restrict__ s0, __hip_bfloat16* d0,
                            const float* __restrict__ s1, __hip_bfloat16* d1,
                            const float* __restrict__ s2, __hip_bfloat16* d2,
                            const float* __restrict__ s3, __hip_bfloat16* d3,
                            int n0, int n1, int n2, int n3) {
  int i = blockIdx.x * 256 + threadIdx.x;
  if (i < n0) { d0[i] = __float2bfloat16(s0[i]); return; }
  i -= n0;
  if (i < n1) { d1[i] = __float2bfloat16(s1[i]); return; }
  i -= n1;
  if (i < n2) { d2[i] = __float2bfloat16(s2[i]); return; }
  i -= n2;
  if (i < n3) d3[i] = __float2bfloat16(s3[i]);
}

// ---------------- fused LayerNorm: fp32 in -> bf16 out ----------------
__global__ __launch_bounds__(256) void ln_kernel(
    const float* __restrict__ x, const float* __restrict__ g,
    const float* __restrict__ b, __hip_bfloat16* __restrict__ out) {
  __shared__ float red[8];
  const int row = blockIdx.x;
  const int tid = threadIdx.x;
  const float* xr = x + (size_t)row * N_EMBD;
  float v0 = xr[tid], v1 = xr[tid + 256], v2 = xr[tid + 512];
  float s = v0 + v1 + v2;
#pragma unroll
  for (int m = 32; m >= 1; m >>= 1) s += __shfl_xor(s, m);
  if ((tid & 63) == 0) red[tid >> 6] = s;
  __syncthreads();
  float mu = (red[0] + red[1] + red[2] + red[3]) * (1.0f / 768.0f);
  float d0 = v0 - mu, d1 = v1 - mu, d2 = v2 - mu;
  float ss = d0 * d0 + d1 * d1 + d2 * d2;
  __syncthreads();
#pragma unroll
  for (int m = 32; m >= 1; m >>= 1) ss += __shfl_xor(ss, m);
  if ((tid & 63) == 0) red[4 + (tid >> 6)] = ss;
  __syncthreads();
  float var = (red[4] + red[5] + red[6] + red[7]) * (1.0f / 768.0f);
  float rstd = rsqrtf(var + 1e-5f);
  __hip_bfloat16* orow = out + (size_t)row * N_EMBD;
  orow[tid]       = __float2bfloat16(d0 * rstd * g[tid]       + b[tid]);
  orow[tid + 256] = __float2bfloat16(d1 * rstd * g[tid + 256] + b[tid + 256]);
  orow[tid + 512] = __float2bfloat16(d2 * rstd * g[tid + 512] + b[tid + 512]);
}

// ---------------- 128x128 GEMM, counted-vmcnt + XOR swizzle + 2D XCD regions ----------------
#define TILE_M 128
#define TILE_N 128
#define TILE_K 32

template <int EPI>
__global__ __launch_bounds__(256) void gemm_bt(
    const __hip_bfloat16* __restrict__ A, const __hip_bfloat16* __restrict__ W,
    const float* __restrict__ bias, const float* __restrict__ resid,
    __hip_bfloat16* __restrict__ outb, float* __restrict__ outf,
    int M, int N, int K) {
  __shared__ __hip_bfloat16 smA[2][TILE_M * TILE_K];
  __shared__ __hip_bfloat16 smB[2][TILE_N * TILE_K];
  const int tid = threadIdx.x;
  const int lane = tid & 63;
  const int wave = tid >> 6;

  const int nbx = gridDim.x;   // col tiles
  const int nby = gridDim.y;   // row tiles
  int brow, bcol;
  if ((nby & 3) == 0 && (nbx & 1) == 0) {
    const int b0 = blockIdx.y * nbx + blockIdx.x;
    const int xcd = b0 & 7;
    const int idx = b0 >> 3;
    const int RW = nbx >> 1;          // region width
    brow = (xcd >> 1) * (nby >> 2) + idx / RW;
    bcol = (xcd & 1) * RW + idx % RW;
  } else {
    brow = blockIdx.y; bcol = blockIdx.x;
  }
  const int m0 = brow * TILE_M;
  const int n0 = bcol * TILE_N;
  const int wr = wave >> 1, wc = wave & 1;

  f32x4 acc[4][4];
#pragma unroll
  for (int i = 0; i < 4; ++i)
#pragma unroll
    for (int j = 0; j < 4; ++j) acc[i][j] = f32x4{0.f, 0.f, 0.f, 0.f};

  const int ar0 = tid >> 2;
  const int ac0 = (((tid & 3) ^ ((ar0 >> 1) & 3))) * 8;
  const __hip_bfloat16* Abase0 = A + (size_t)(m0 + ar0) * K + ac0;
  const __hip_bfloat16* Abase1 = A + (size_t)(m0 + 64 + ar0) * K + ac0;
  const __hip_bfloat16* Wbase0 = W + (size_t)(n0 + ar0) * K + ac0;
  const __hip_bfloat16* Wbase1 = W + (size_t)(n0 + 64 + ar0) * K + ac0;

  auto stage = [&](int buf, int k0) {
    gload_lds16(Abase0 + k0, &smA[buf][wave * 512]);
    gload_lds16(Abase1 + k0, &smA[buf][2048 + wave * 512]);
    gload_lds16(Wbase0 + k0, &smB[buf][wave * 512]);
    gload_lds16(Wbase1 + k0, &smB[buf][2048 + wave * 512]);
  };

  const int rA = lane & 15;
  const int fq = lane >> 4;
  const int nk = K / TILE_K;

  stage(0, 0);

  int cur = 0;
  for (int t = 0; t < nk; ++t) {
    asm volatile("s_waitcnt vmcnt(0)" ::: "memory");
    asm volatile("s_barrier" ::: "memory");
    if (t + 1 < nk) stage(cur ^ 1, (t + 1) * TILE_K);

    s16x8 af[4], bfr[4];
#pragma unroll
    for (int mi = 0; mi < 4; ++mi) {
      const int row = wr * 64 + mi * 16 + rA;
      const int g = fq ^ ((row >> 1) & 3);
      af[mi] = *(const s16x8*)&smA[cur][row * TILE_K + g * 8];
    }
#pragma unroll
    for (int ni = 0; ni < 4; ++ni) {
      const int row = wc * 64 + ni * 16 + rA;
      const int g = fq ^ ((row >> 1) & 3);
      bfr[ni] = *(const s16x8*)&smB[cur][row * TILE_K + g * 8];
    }
#pragma unroll
    for (int mi = 0; mi < 4; ++mi)
#pragma unroll
      for (int ni = 0; ni < 4; ++ni)
        acc[mi][ni] = __builtin_amdgcn_mfma_f32_16x16x32_bf16(
            af[mi], bfr[ni], acc[mi][ni], 0, 0, 0);
    cur ^= 1;
  }

  const int crow = (lane >> 4) * 4;
  const int ccol = lane & 15;
#pragma unroll
  for (int mi = 0; mi < 4; ++mi) {
#pragma unroll
    for (int ni = 0; ni < 4; ++ni) {
      const int col = n0 + wc * 64 + ni * 16 + ccol;
      const float bv = bias[col];
#pragma unroll
      for (int j = 0; j < 4; ++j) {
        const int row = m0 + wr * 64 + mi * 16 + crow + j;
        float v = acc[mi][ni][j] + bv;
        const size_t o = (size_t)row * N + col;
        if (EPI == 0) {
          outb[o] = __float2bfloat16(v);
        } else if (EPI == 1) {
          outb[o] = __float2bfloat16(gelu_f(v));
        } else {
          outf[o] = resid[o] + v;
        }
      }
    }
  }
}

// ---------------- MFMA causal flash attention, v5 ----------------
// R18 structure + VALU trim: P-pack via __float22bfloat162_rn (pk-cvt,
// halves cvt count, removes or/shift packing) and max3-shaped fmax tree.
#define AP 72

__global__ __launch_bounds__(256) void attn_mfma(
    const __hip_bfloat16* __restrict__ qkv, __hip_bfloat16* __restrict__ y,
    int T) {
  __shared__ __hip_bfloat16 ks[2][64 * AP];
  __shared__ __hip_bfloat16 vt[2][64 * AP];
  __shared__ __hip_bfloat16 ps[4][16 * AP];
  const int tid = threadIdx.x;
  const int lane = tid & 63;
  const int wave = tid >> 6;

  // chunked XCD swizzle: each XCD owns 96 consecutive virt ids (6 bh's)
  const int nbx = gridDim.x;  // 16
  const int nwg = nbx * gridDim.y;
  int bid = blockIdx.y * nbx + blockIdx.x;
  if ((nwg & 7) == 0) bid = (bid & 7) * (nwg >> 3) + (bid >> 3);
  const int bx = bid % nbx;
  const int bh = bid / nbx;
  const int b = bh / N_HEADS, h = bh % N_HEADS;

  const int nq = T / 64;
  const int qa0 = bx * 64;
  const int qb0 = (nq - 1 - bx) * 64;
  const size_t ldq = 3 * N_EMBD;
  const __hip_bfloat16* qb_ = qkv + (size_t)b * T * ldq + h * HEAD_DIM;
  const __hip_bfloat16* kb = qb_ + N_EMBD;
  const __hip_bfloat16* vb = qb_ + 2 * N_EMBD;

  const int fr = lane & 15;
  const int fo = (lane >> 4) * 8;
  const int crow = (lane >> 4) * 4;

  const float qs = 0.125f * 1.44269504f;
  auto loadq = [&](int qrow, int o) -> s16x8 {
    s16x8 v = *(const s16x8*)(qb_ + (size_t)qrow * ldq + o);
    s16x8 r;
#pragma unroll
    for (int i = 0; i < 8; ++i) {
      float f = bf2f((unsigned short)v[i]) * qs;
      __hip_bfloat16 hb = __float2bfloat16(f);
      r[i] = *reinterpret_cast<short*>(&hb);
    }
    return r;
  };
  s16x8 qfa0 = loadq(qa0 + wave * 16 + fr, fo);
  s16x8 qfa1 = loadq(qa0 + wave * 16 + fr, fo + 32);
  s16x8 qfb0 = loadq(qb0 + wave * 16 + fr, fo);
  s16x8 qfb1 = loadq(qb0 + wave * 16 + fr, fo + 32);

  f32x4 oa[4], ob[4];
#pragma unroll
  for (int j = 0; j < 4; ++j) {
    oa[j] = f32x4{0.f, 0.f, 0.f, 0.f};
    ob[j] = f32x4{0.f, 0.f, 0.f, 0.f};
  }
  float m_a = -1e30f, l_a = 0.f, m_b = -1e30f, l_b = 0.f;

  s16x8 kr0, kr1, vr0, vr1;
  const int krow0 = tid >> 3;
  const int kcol = (tid & 7) * 8;
  const int vkey = 2 * (lane & 31);
  const int vd0 = wave * 16 + (lane >> 5) * 8;

  auto loadKV = [&](int kt) {
    kr0 = *(const s16x8*)(kb + (size_t)(kt + krow0) * ldq + kcol);
    kr1 = *(const s16x8*)(kb + (size_t)(kt + 32 + krow0) * ldq + kcol);
    vr0 = *(const s16x8*)(vb + (size_t)(kt + vkey) * ldq + vd0);
    vr1 = *(const s16x8*)(vb + (size_t)(kt + vkey + 1) * ldq + vd0);
  };
  auto writeKV = [&](int bufi) {
    *(s16x8*)&ks[bufi][krow0 * AP + kcol] = kr0;
    *(s16x8*)&ks[bufi][(32 + krow0) * AP + kcol] = kr1;
#pragma unroll
    for (int i = 0; i < 8; ++i) {
      unsigned u = (unsigned short)vr0[i] | ((unsigned)(unsigned short)vr1[i] << 16);
      *(unsigned*)&vt[bufi][(vd0 + i) * AP + vkey] = u;
    }
  };

  auto process = [&](int bufi, const s16x8& q0f, const s16x8& q1f,
                     f32x4 (&o)[4], float& m_, float& l_, int tq0, bool diag,
                     int kt) {
    f32x4 sv[4];
#pragma unroll
    for (int sub = 0; sub < 4; ++sub) {
      s16x8 k0 = *(const s16x8*)&ks[bufi][(sub * 16 + fr) * AP + fo];
      s16x8 k1 = *(const s16x8*)&ks[bufi][(sub * 16 + fr) * AP + 32 + fo];
      f32x4 acc = f32x4{0.f, 0.f, 0.f, 0.f};
      acc = __builtin_amdgcn_mfma_f32_16x16x32_bf16(k0, q0f, acc, 0, 0, 0);
      acc = __builtin_amdgcn_mfma_f32_16x16x32_bf16(k1, q1f, acc, 0, 0, 0);
      sv[sub] = acc;
    }
    const int qg = tq0 + wave * 16 + fr;
    if (diag) {
#pragma unroll
      for (int sub = 0; sub < 4; ++sub)
#pragma unroll
        for (int j = 0; j < 4; ++j)
          if (kt + sub * 16 + crow + j > qg) sv[sub][j] = -1e30f;
    }
    // row max: max3-shaped tree (clang fuses fmaxf(fmaxf(a,b),c) -> v_max3)
    float g0 = fmaxf(fmaxf(sv[0][0], sv[0][1]), fmaxf(sv[0][2], sv[0][3]));
    float g1 = fmaxf(fmaxf(sv[1][0], sv[1][1]), fmaxf(sv[1][2], sv[1][3]));
    float g2 = fmaxf(fmaxf(sv[2][0], sv[2][1]), fmaxf(sv[2][2], sv[2][3]));
    float g3 = fmaxf(fmaxf(sv[3][0], sv[3][1]), fmaxf(sv[3][2], sv[3][3]));
    float t = fmaxf(fmaxf(g0, g1), fmaxf(g2, g3));
    t = fmaxf(t, __shfl_xor(t, 16));
    t = fmaxf(t, __shfl_xor(t, 32));
    const bool resc = t > m_ + 8.0f;  // T13 defer-max
    const float corr = resc ? exp2f(m_ - t) : 1.0f;
    if (resc) m_ = t;
    float rs = 0.f;
#pragma unroll
    for (int sub = 0; sub < 4; ++sub) {
      float p0 = exp2f(sv[sub][0] - m_);
      float p1 = exp2f(sv[sub][1] - m_);
      float p2 = exp2f(sv[sub][2] - m_);
      float p3 = exp2f(sv[sub][3] - m_);
      rs += (p0 + p1) + (p2 + p3);
      // pk-cvt: v_cvt_pk_bf16_f32 x2 (replaces 4 scalar cvt + or/shift pack)
      __hip_bfloat162 pk01 = __float22bfloat162_rn(float2{p0, p1});
      __hip_bfloat162 pk23 = __float22bfloat162_rn(float2{p2, p3});
      uint2 u;
      u.x = *reinterpret_cast<unsigned*>(&pk01);
      u.y = *reinterpret_cast<unsigned*>(&pk23);
      *(uint2*)&ps[wave][fr * AP + sub * 16 + crow] = u;  // ds_write_b64
    }
    rs += __shfl_xor(rs, 16);
    rs += __shfl_xor(rs, 32);
    l_ = l_ * corr + rs;
    if (__any(resc)) {
#pragma unroll
      for (int j = 0; j < 4; ++j) {
        const float cj = __shfl(corr, (lane & 0x30) | (crow + j));
#pragma unroll
        for (int ds = 0; ds < 4; ++ds) o[ds][j] *= cj;
      }
    }
    s16x8 pf0 = *(const s16x8*)&ps[wave][fr * AP + fo];
    s16x8 pf1 = *(const s16x8*)&ps[wave][fr * AP + 32 + fo];
#pragma unroll
    for (int ds = 0; ds < 4; ++ds) {
      s16x8 v0 = *(const s16x8*)&vt[bufi][(ds * 16 + fr) * AP + fo];
      s16x8 v1 = *(const s16x8*)&vt[bufi][(ds * 16 + fr) * AP + 32 + fo];
      o[ds] = __builtin_amdgcn_mfma_f32_16x16x32_bf16(pf0, v0, o[ds], 0, 0, 0);
      o[ds] = __builtin_amdgcn_mfma_f32_16x16x32_bf16(pf1, v1, o[ds], 0, 0, 0);
    }
  };

  loadKV(0);
  writeKV(0);
  __syncthreads();
  int cur = 0;
  for (int kt = 0; kt <= qb0; kt += 64) {
    const bool hasnext = (kt + 64 <= qb0);
    if (hasnext) loadKV(kt + 64);
    if (kt <= qa0)
      process(cur, qfa0, qfa1, oa, m_a, l_a, qa0, kt == qa0, kt);
    process(cur, qfb0, qfb1, ob, m_b, l_b, qb0, kt == qb0, kt);
    if (hasnext) writeKV(cur ^ 1);
    __syncthreads();
    cur ^= 1;
  }

#pragma unroll
  for (int j = 0; j < 4; ++j) {
    const float la_j = __shfl(l_a, (lane & 0x30) | (crow + j));
    const float lb_j = __shfl(l_b, (lane & 0x30) | (crow + j));
    const float inva = 1.0f / la_j;
    const float invb = 1.0f / lb_j;
    __hip_bfloat16* ya =
        y + (size_t)(b * T + qa0 + wave * 16 + crow + j) * N_EMBD + h * HEAD_DIM;
    __hip_bfloat16* yb =
        y + (size_t)(b * T + qb0 + wave * 16 + crow + j) * N_EMBD + h * HEAD_DIM;
#pragma unroll
    for (int ds = 0; ds < 4; ++ds) {
      ya[ds * 16 + fr] = __float2bfloat16(oa[ds][j] * inva);
      yb[ds * 16 + fr] = __float2bfloat16(ob[ds][j] * invb);
    }
  }
}

// ---------------- launch ----------------
extern "C" void kernel_launch(void* const* d_in, const int* in_sizes, int n_in,
                              void* d_out, int out_size, void* d_ws,
                              size_t ws_size, hipStream_t stream) {
  const int B = 4, T = 2048, C = N_EMBD;
  const int M = B * T;  // 8192

  const float* x      = (const float*)d_in[0];
  const float* ln1_g  = (const float*)d_in[1];
  const float* ln1_b  = (const float*)d_in[2];
  const float* attn_w = (const float*)d_in[3];
  const float* attn_b = (const float*)d_in[4];
  const float* proj_w = (const float*)d_in[5];
  const float* proj_b = (const float*)d_in[6];
  const float* ln2_g  = (const float*)d_in[7];
  const float* ln2_b  = (const float*)d_in[8];
  const float* fc_w   = (const float*)d_in[9];
  const float* fc_b   = (const float*)d_in[10];
  const float* fc2_w  = (const float*)d_in[11];
  const float* fc2_b  = (const float*)d_in[12];
  float* out = (float*)d_out;

  char* p = (char*)d_ws;
  size_t off = 0;
  auto take = [&](size_t bytes) -> void* {
    void* q = p + off;
    off += (bytes + 1023) & ~(size_t)1023;
    return q;
  };

  __hip_bfloat16* wqkv  = (__hip_bfloat16*)take((size_t)3 * C * C * 2);
  __hip_bfloat16* wproj = (__hip_bfloat16*)take((size_t)C * C * 2);
  __hip_bfloat16* wfc   = (__hip_bfloat16*)take((size_t)4 * C * C * 2);
  __hip_bfloat16* wfc2  = (__hip_bfloat16*)take((size_t)4 * C * C * 2);
  __hip_bfloat16* hbuf  = (__hip_bfloat16*)take((size_t)M * C * 2);
  __hip_bfloat16* big   = (__hip_bfloat16*)take((size_t)M * 4 * C * 2);
  __hip_bfloat16* ybuf  = (__hip_bfloat16*)take((size_t)M * C * 2);
  float*          x1    = (float*)take((size_t)M * C * 4);

  {
    const int n0 = 3 * C * C, n1 = C * C, n2 = 4 * C * C, n3 = 4 * C * C;
    const int ntot = n0 + n1 + n2 + n3;
    cvt4_kernel<<<(ntot + 255) / 256, 256, 0, stream>>>(
        attn_w, wqkv, proj_w, wproj, fc_w, wfc, fc2_w, wfc2, n0, n1, n2, n3);
  }

  ln_kernel<<<M, 256, 0, stream>>>(x, ln1_g, ln1_b, hbuf);
  gemm_bt<0><<<dim3(3 * C / TILE_N, M / TILE_M), 256, 0, stream>>>(
      hbuf, wqkv, attn_b, nullptr, big, nullptr, M, 3 * C, C);
  attn_mfma<<<dim3(T / 128, B * N_HEADS), 256, 0, stream>>>(big, ybuf, T);
  gemm_bt<2><<<dim3(C / TILE_N, M / TILE_M), 256, 0, stream>>>(
      ybuf, wproj, proj_b, x, nullptr, x1, M, C, C);
  ln_kernel<<<M, 256, 0, stream>>>(x1, ln2_g, ln2_b, hbuf);
  gemm_bt<1><<<dim3(4 * C / TILE_N, M / TILE_M), 256, 0, stream>>>(
      hbuf, wfc, fc_b, nullptr, big, nullptr, M, 4 * C, C);
  gemm_bt<2><<<dim3(C / TILE_N, M / TILE_M), 256, 0, stream>>>(
      big, wfc2, fc2_b, x1, nullptr, out, M, C, 4 * C);
}